// Round 6
// baseline (358.264 us; speedup 1.0000x reference)
//
#include <hip/hip_runtime.h>
#include <hip/hip_bf16.h>
#include <cstdint>
#include <cstddef>

// ---------------- problem constants ----------------
#define D_MODEL 1024
#define D_STATE 64
#define D_INNER 2048
#define BATCH   4
#define SEQ     2048
#define MROWS   (BATCH*SEQ)      // 8192
#define CHUNK   32               // scan chunk length
#define NCHUNK  (SEQ/CHUNK)      // 64 chunks per batch

typedef __bf16 bf16x8 __attribute__((ext_vector_type(8)));
typedef float  f32x4  __attribute__((ext_vector_type(4)));

__device__ __forceinline__ float bf2f(unsigned short u) {
    union { unsigned int i; float f; } v; v.i = ((unsigned int)u) << 16; return v.f;
}
__device__ __forceinline__ unsigned short f2bf(float f) {
    union { float f; unsigned int i; } v; v.f = f;
    unsigned int r = v.i + 0x7fff + ((v.i >> 16) & 1);   // round-to-nearest-even
    return (unsigned short)(r >> 16);
}
__device__ __forceinline__ float lo16(unsigned u){ return bf2f((unsigned short)(u & 0xffffu)); }
__device__ __forceinline__ float hi16(unsigned u){ return bf2f((unsigned short)(u >> 16)); }
__device__ __forceinline__ unsigned pack2(float a, float b){
    return (unsigned)f2bf(a) | ((unsigned)f2bf(b) << 16);
}

// ---------------- f32 -> bf16 bulk convert (4 elems/thread) ----------------
__global__ __launch_bounds__(256) void f32_to_bf16(const float* __restrict__ in,
                                                   unsigned short* __restrict__ out) {
    size_t i = ((size_t)blockIdx.x * 256 + threadIdx.x) * 4;
    float4 v = *(const float4*)(in + i);
    uint2 o; o.x = pack2(v.x, v.y); o.y = pack2(v.z, v.w);
    *(uint2*)(out + i) = o;
}

// ---------------- transpose f32 -> bf16: out[c][r] = bf16(in[r][c]) ----------------
__global__ void transpose_f32_bf16(const float* __restrict__ in,
                                   unsigned short* __restrict__ out, int rows, int cols) {
    __shared__ float t[32][33];
    int bx = blockIdx.x * 32, by = blockIdx.y * 32;
    int tx = threadIdx.x, ty = threadIdx.y;
    int r = by + ty, c = bx + tx;
    if (r < rows && c < cols) t[ty][tx] = in[(size_t)r * cols + c];
    __syncthreads();
    int ro = bx + ty, co = by + tx;
    if (ro < cols && co < rows) out[(size_t)ro * rows + co] = f2bf(t[tx][ty]);
}

// ---------------- transpose W_xp cols 1..128: out[j][k] = bf16(wxp[k][1+j]) -------------
__global__ void transpose_wxp(const float* __restrict__ wxp,
                              unsigned short* __restrict__ out) {
    __shared__ float t[32][33];
    int j0 = blockIdx.x * 32, k0 = blockIdx.y * 32;
    int tx = threadIdx.x, ty = threadIdx.y;
    t[ty][tx] = wxp[(size_t)(k0 + ty) * 129 + 1 + j0 + tx];
    __syncthreads();
    out[(size_t)(j0 + ty) * 2048 + k0 + tx] = f2bf(t[tx][ty]);
}

// ---------------- extract w0 (delta weight column) ----------------
__global__ void extract_w0(const float* __restrict__ wxp, float* __restrict__ w0f) {
    int k = blockIdx.x * 256 + threadIdx.x;
    if (k < D_INNER) w0f[k] = wxp[(size_t)k * 129];
}

// ---------------- MFMA GEMM (TN): C[M][N] = A[M][K] @ BT[N][K]^T ----------------
#define BM 128
#define BN 128
enum { EPI_PLAIN = 0, EPI_F32OUT = 3, EPI_F32ACC = 4 };

__device__ __forceinline__ void gload_lds16(const void* g, void* l) {
    __builtin_amdgcn_global_load_lds((const __attribute__((address_space(1))) void*)g,
                                     (__attribute__((address_space(3))) void*)l, 16, 0, 0);
}

template<int EPI>
__global__ __launch_bounds__(256) void gemm_tn(
    const unsigned short* __restrict__ A,   // [M][K] lda (bf16)
    const unsigned short* __restrict__ BT,  // [N][K] ldb (bf16)
    void* __restrict__ Cv,                  // [M][N] ldc
    int M, int N, int kchunk, int lda, int ldb, int ldc)
{
    __shared__ __align__(16) unsigned short As0[BM * 32];
    __shared__ __align__(16) unsigned short As1[BM * 32];
    __shared__ __align__(16) unsigned short Bs0[BN * 32];
    __shared__ __align__(16) unsigned short Bs1[BN * 32];
    const int tid  = threadIdx.x;
    const int wave = tid >> 6, lane = tid & 63;
    const int row0 = blockIdx.y * BM, col0 = blockIdx.x * BN;
    const int wr = (wave >> 1) * 64, wc = (wave & 1) * 64;
    const int srow = lane >> 2;          // 0..15
    const int scol = (lane & 3) * 8;     // 0,8,16,24

    f32x4 acc[4][4];
    #pragma unroll
    for (int i = 0; i < 4; ++i)
        #pragma unroll
        for (int j = 0; j < 4; ++j)
            #pragma unroll
            for (int r = 0; r < 4; ++r) acc[i][j][r] = 0.0f;

    const int kbeg = blockIdx.z * kchunk;
    for (int k0 = kbeg; k0 < kbeg + kchunk; k0 += 64) {
        #pragma unroll
        for (int qi = 0; qi < 2; ++qi) {
            int q = wave * 2 + qi;   // 0..7: 16-row group of the 128-row tile
            const unsigned short* gA = A  + (size_t)(row0 + q*16 + srow) * lda + (k0 + scol);
            const unsigned short* gB = BT + (size_t)(col0 + q*16 + srow) * ldb + (k0 + scol);
            gload_lds16(gA,      &As0[q * 512]);
            gload_lds16(gA + 32, &As1[q * 512]);
            gload_lds16(gB,      &Bs0[q * 512]);
            gload_lds16(gB + 32, &Bs1[q * 512]);
        }
        __syncthreads();
        bf16x8 af0[4], af1[4], bf0[4], bf1[4];
        const int lro = lane & 15, lko = (lane >> 4) * 8;
        #pragma unroll
        for (int t = 0; t < 4; ++t) {
            af0[t] = *(const bf16x8*)&As0[(wr + t*16 + lro) * 32 + lko];
            af1[t] = *(const bf16x8*)&As1[(wr + t*16 + lro) * 32 + lko];
            bf0[t] = *(const bf16x8*)&Bs0[(wc + t*16 + lro) * 32 + lko];
            bf1[t] = *(const bf16x8*)&Bs1[(wc + t*16 + lro) * 32 + lko];
        }
        #pragma unroll
        for (int i = 0; i < 4; ++i)
            #pragma unroll
            for (int j = 0; j < 4; ++j) {
                acc[i][j] = __builtin_amdgcn_mfma_f32_16x16x32_bf16(af0[i], bf0[j], acc[i][j], 0, 0, 0);
                acc[i][j] = __builtin_amdgcn_mfma_f32_16x16x32_bf16(af1[i], bf1[j], acc[i][j], 0, 0, 0);
            }
        __syncthreads();
    }

    const int r0 = (lane >> 4) * 4, cl = lane & 15;
    #pragma unroll
    for (int i = 0; i < 4; ++i) {
        #pragma unroll
        for (int j = 0; j < 4; ++j) {
            #pragma unroll
            for (int r = 0; r < 4; ++r) {
                int gr = row0 + wr + i*16 + r0 + r;
                int gc = col0 + wc + j*16 + cl;
                float v = acc[i][j][r];
                if (EPI == EPI_F32OUT)      ((float*)Cv)[(size_t)gr * ldc + gc] = v;
                else if (EPI == EPI_F32ACC) ((float*)Cv + (size_t)blockIdx.z * M * ldc)[(size_t)gr * ldc + gc] = v;
                else                        ((unsigned short*)Cv)[(size_t)gr * ldc + gc] = f2bf(v);
            }
        }
    }
}

// ---------------- reduce split-K partials -> bf16 ----------------
__global__ __launch_bounds__(256) void reduce_proj(const float* __restrict__ part,
                                                   unsigned short* __restrict__ out) {
    size_t i = ((size_t)blockIdx.x * 256 + threadIdx.x) * 4;
    const size_t stride = (size_t)MROWS * 128;
    float4 s = *(const float4*)(part + i);
    #pragma unroll
    for (int p = 1; p < 4; ++p) {
        float4 v = *(const float4*)(part + p * stride + i);
        s.x += v.x; s.y += v.y; s.z += v.z; s.w += v.w;
    }
    uint2 o; o.x = pack2(s.x, s.y); o.y = pack2(s.z, s.w);
    *(uint2*)(out + i) = o;
}

// ---------------- delta: dA[m] = softplus(xi[m,:]. w0) * A ; abar = exp(dA) ----------------
__global__ __launch_bounds__(256) void delta_kernel(
    const unsigned short* __restrict__ xz, const float* __restrict__ w0f,
    const float* __restrict__ A_log,
    float* __restrict__ dA, float* __restrict__ abar)
{
    int row  = blockIdx.x * 4 + (threadIdx.x >> 6);
    int lane = threadIdx.x & 63;
    const unsigned short* xi = xz + (size_t)row * (2 * D_INNER);
    float s = 0.f;
    #pragma unroll
    for (int step = 0; step < 4; ++step) {
        int oct = step * 64 + lane;          // 256 octets of 8 bf16
        uint4 u = *(const uint4*)(xi + oct * 8);
        const float4* pw = (const float4*)(w0f + oct * 8);
        float4 wa = pw[0], wb = pw[1];
        s += lo16(u.x)*wa.x + hi16(u.x)*wa.y + lo16(u.y)*wa.z + hi16(u.y)*wa.w
           + lo16(u.z)*wb.x + hi16(u.z)*wb.y + lo16(u.w)*wb.z + hi16(u.w)*wb.w;
    }
    #pragma unroll
    for (int off = 32; off > 0; off >>= 1) s += __shfl_xor(s, off);
    if (lane == 0) {
        float Av = -expf(A_log[0]);
        float d  = (s > 20.f) ? s : log1pf(expf(s));
        float da = d * Av;
        dA[row] = da;
        abar[row] = expf(da);
    }
}

// ---------------- chunk aux: sfx[t]=exp(sum_{s>t} dA), P=exp(sum dA) per chunk ----------
__global__ void chunk_aux(const float* __restrict__ dA,
                          float* __restrict__ sfx, float* __restrict__ P) {
    int idx = threadIdx.x;                    // chunk id: 0..255 = b*NCHUNK + j
    float suf = 0.f;
    for (int t = CHUNK - 1; t >= 0; --t) {
        sfx[idx * CHUNK + t] = expf(suf);
        suf += dA[idx * CHUNK + t];
    }
    P[idx] = expf(suf);
}

// ============ fused B/C expansion + scan kernels ============
// Block geometry: 128 channels x 64 rows (2 chunks) x batch.
#define CB 128
#define R2 64
#define PST 136   // padded LDS row stride (elems)

// ---------------- pass 1: carry[j][c] = sum_t sfx[t] * B[t][c] * xi[t][c] ----------------
__global__ __launch_bounds__(256) void bc_carry(
    const unsigned short* __restrict__ proj,  // [MROWS][128] bf16 (B_raw|C_raw)
    const unsigned short* __restrict__ wbT,   // [2048][64] bf16
    const unsigned short* __restrict__ xz,    // [MROWS][4096] bf16 (xi = cols 0..2047)
    const float* __restrict__ sfx,            // [MROWS]
    float* __restrict__ carry)                // [BATCH*NCHUNK][2048]
{
    __shared__ unsigned short Ps[R2 * PST];   // proj tile (cols 0..127 valid)
    __shared__ unsigned short Xs[R2 * PST];   // xi tile (channel slice)
    const int cb = blockIdx.x, j2 = blockIdx.y, b = blockIdx.z;
    const int c0 = cb * CB;
    const int srow = b * SEQ + j2 * R2;
    const int tid = threadIdx.x, wave = tid >> 6, lane = tid & 63;

    #pragma unroll
    for (int i = 0; i < 4; ++i) {             // stage proj tile 64x128
        int e = i * 2048 + tid * 8, r = e >> 7, c = e & 127;
        uint4 v = *(const uint4*)(proj + (size_t)(srow + r) * 128 + c);
        *(uint4*)&Ps[r * PST + c] = v;
    }
    #pragma unroll
    for (int i = 0; i < 4; ++i) {             // stage xi tile 64x128
        int e = i * 2048 + tid * 8, r = e >> 7, c = e & 127;
        uint4 v = *(const uint4*)(xz + (size_t)(srow + r) * (2*D_INNER) + c0 + c);
        *(uint4*)&Xs[r * PST + c] = v;
    }
    __syncthreads();

    const int mt0 = (wave >> 1) * 2;          // waves 0,1 -> chunk A rows; 2,3 -> chunk B
    const int nb  = (wave & 1) * 64;
    const int lr = lane & 15, lq = lane >> 4;

    f32x4 acc[2][4];
    #pragma unroll
    for (int mi = 0; mi < 2; ++mi)
        #pragma unroll
        for (int ni = 0; ni < 4; ++ni)
            #pragma unroll
            for (int r = 0; r < 4; ++r) acc[mi][ni][r] = 0.0f;

    #pragma unroll
    for (int s = 0; s < 2; ++s) {             // K=64: two k-steps
        bf16x8 af[2], bfr[4];
        #pragma unroll
        for (int mi = 0; mi < 2; ++mi)
            af[mi] = *(const bf16x8*)&Ps[((mt0+mi)*16 + lr) * PST + s*32 + lq*8];
        #pragma unroll
        for (int ni = 0; ni < 4; ++ni)
            bfr[ni] = *(const bf16x8*)(wbT + (size_t)(c0 + nb + ni*16 + lr) * 64 + s*32 + lq*8);
        #pragma unroll
        for (int mi = 0; mi < 2; ++mi)
            #pragma unroll
            for (int ni = 0; ni < 4; ++ni)
                acc[mi][ni] = __builtin_amdgcn_mfma_f32_16x16x32_bf16(af[mi], bfr[ni], acc[mi][ni], 0, 0, 0);
    }

    float w8[2][4];
    #pragma unroll
    for (int mi = 0; mi < 2; ++mi)
        #pragma unroll
        for (int r = 0; r < 4; ++r)
            w8[mi][r] = sfx[srow + (mt0+mi)*16 + lq*4 + r];

    float csum[4];
    #pragma unroll
    for (int ni = 0; ni < 4; ++ni) {
        float s = 0.f;
        #pragma unroll
        for (int mi = 0; mi < 2; ++mi)
            #pragma unroll
            for (int r = 0; r < 4; ++r) {
                int row = (mt0+mi)*16 + lq*4 + r;
                float xv = bf2f(Xs[row * PST + nb + ni*16 + lr]);
                s += w8[mi][r] * acc[mi][ni][r] * xv;
            }
        s += __shfl_xor(s, 16);
        s += __shfl_xor(s, 32);
        csum[ni] = s;
    }
    if (lane < 16) {
        int jj = j2 * 2 + (mt0 >> 1);
        float* dst = carry + ((size_t)(b * NCHUNK + jj)) * D_INNER + c0 + nb;
        #pragma unroll
        for (int ni = 0; ni < 4; ++ni) dst[ni*16 + lane] = csum[ni];
    }
}

// ---------------- pass 2: inter-chunk scan; carry <- exclusive prefix (h-init) ------
__global__ __launch_bounds__(256) void scan_chunks(float* __restrict__ carry,
                                                   const float* __restrict__ P) {
    int c = blockIdx.x * 256 + threadIdx.x;
    int b = blockIdx.y;
    float H = 0.f;
    for (int j = 0; j < NCHUNK; ++j) {
        size_t idx = ((size_t)(b * NCHUNK + j)) * D_INNER + c;
        float cr = carry[idx];
        carry[idx] = H;                         // exclusive: h-init for chunk j
        H = P[b * NCHUNK + j] * H + cr;
    }
}

// ---------------- pass 3: MFMA-recompute B,C (f32 regs); register scan with shuffle
//                  carries; vectorized gated epilogue -> ypre ----------------
__global__ __launch_bounds__(256) void bc_scan(
    const unsigned short* __restrict__ proj,
    const unsigned short* __restrict__ wbT,   // [2048][64]
    const unsigned short* __restrict__ wcT,   // [2048][64]
    const unsigned short* __restrict__ xz,
    const float* __restrict__ Dvf,
    const float* __restrict__ abar,
    const float* __restrict__ carry,
    unsigned short* __restrict__ ypre)        // [MROWS][2048]
{
    __shared__ unsigned short Ps[R2 * PST];   // proj tile, later reused as Y tile
    __shared__ unsigned short Xs[R2 * PST];   // xi tile
    __shared__ float Aab[R2];                 // abar for the block's 64 rows
    const int cb = blockIdx.x, j2 = blockIdx.y, b = blockIdx.z;
    const int c0 = cb * CB;
    const int srow = b * SEQ + j2 * R2;
    const int tid = threadIdx.x, wave = tid >> 6, lane = tid & 63;

    #pragma unroll
    for (int i = 0; i < 4; ++i) {
        int e = i * 2048 + tid * 8, r = e >> 7, c = e & 127;
        uint4 v = *(const uint4*)(proj + (size_t)(srow + r) * 128 + c);
        *(uint4*)&Ps[r * PST + c] = v;
    }
    #pragma unroll
    for (int i = 0; i < 4; ++i) {
        int e = i * 2048 + tid * 8, r = e >> 7, c = e & 127;
        uint4 v = *(const uint4*)(xz + (size_t)(srow + r) * (2*D_INNER) + c0 + c);
        *(uint4*)&Xs[r * PST + c] = v;
    }
    if (tid < R2) Aab[tid] = abar[srow + tid];
    __syncthreads();

    const int hh = wave >> 1;                 // chunk half within block (0/1)
    const int nb = (wave & 1) * 64;
    const int lr = lane & 15, lq = lane >> 4;
    const int jj = j2 * 2 + hh;

    // ---- MFMA: B-tile and C-tile into f32 registers (C-layout) ----
    f32x4 accB[2][4], accC[2][4];
    #pragma unroll
    for (int mi = 0; mi < 2; ++mi)
        #pragma unroll
        for (int ni = 0; ni < 4; ++ni)
            #pragma unroll
            for (int r = 0; r < 4; ++r) { accB[mi][ni][r] = 0.f; accC[mi][ni][r] = 0.f; }
    #pragma unroll
    for (int s = 0; s < 2; ++s) {
        bf16x8 afB[2], afC[2], bB[4], bC[4];
        #pragma unroll
        for (int mi = 0; mi < 2; ++mi) {
            afB[mi] = *(const bf16x8*)&Ps[(hh*32 + mi*16 + lr) * PST + s*32 + lq*8];
            afC[mi] = *(const bf16x8*)&Ps[(hh*32 + mi*16 + lr) * PST + 64 + s*32 + lq*8];
        }
        #pragma unroll
        for (int ni = 0; ni < 4; ++ni) {
            bB[ni] = *(const bf16x8*)(wbT + (size_t)(c0 + nb + ni*16 + lr) * 64 + s*32 + lq*8);
            bC[ni] = *(const bf16x8*)(wcT + (size_t)(c0 + nb + ni*16 + lr) * 64 + s*32 + lq*8);
        }
        #pragma unroll
        for (int mi = 0; mi < 2; ++mi)
            #pragma unroll
            for (int ni = 0; ni < 4; ++ni) {
                accB[mi][ni] = __builtin_amdgcn_mfma_f32_16x16x32_bf16(afB[mi], bB[ni], accB[mi][ni], 0, 0, 0);
                accC[mi][ni] = __builtin_amdgcn_mfma_f32_16x16x32_bf16(afC[mi], bC[ni], accC[mi][ni], 0, 0, 0);
            }
    }
    __syncthreads();   // all waves done reading Ps -> safe to reuse as Y

    // ---- decay values & prefix products (channel-independent) ----
    float ar[2][4], pa[2][4];
    #pragma unroll
    for (int mi = 0; mi < 2; ++mi) {
        float p = 1.f;
        #pragma unroll
        for (int r = 0; r < 4; ++r) {
            ar[mi][r] = Aab[hh*32 + mi*16 + lq*4 + r];
            p *= ar[mi][r];
            pa[mi][r] = p;
        }
    }
    // A-part Hillis-Steele across quads (segments in row order: s = mi*4 + lq)
    float A0[2], A1[2], A2[2], exA[2];
    #pragma unroll
    for (int mi = 0; mi < 2; ++mi) {
        A0[mi] = pa[mi][3];
        float p = __shfl_up(A0[mi], 16);
        A1[mi] = (lq >= 1) ? p * A0[mi] : A0[mi];
        float p2 = __shfl_up(A1[mi], 32);
        A2[mi] = (lq >= 2) ? p2 * A1[mi] : A1[mi];
        float e = __shfl_up(A2[mi], 16);
        exA[mi] = (lq == 0) ? 1.f : e;
    }
    const float TA = __shfl(A2[0], 48 + lr);   // inclusive product over chunk-half 0 (rows 0..15)

    // ---- per-channel scan + y ----
    #pragma unroll
    for (int ni = 0; ni < 4; ++ni) {
        const int ch = nb + ni*16 + lr;
        float H0 = carry[((size_t)(b * NCHUNK + jj)) * D_INNER + c0 + ch];
        float hloc[2][4];
        #pragma unroll
        for (int mi = 0; mi < 2; ++mi) {
            float h = 0.f;
            #pragma unroll
            for (int r = 0; r < 4; ++r) {
                float xv = bf2f(Xs[(hh*32 + mi*16 + lq*4 + r) * PST + ch]);
                h = fmaf(ar[mi][r], h, accB[mi][ni][r] * xv);
                hloc[mi][r] = h;
            }
        }
        float exB[2], TB = 0.f;
        #pragma unroll
        for (int mi = 0; mi < 2; ++mi) {
            float Bv = hloc[mi][3];
            float p = __shfl_up(Bv, 16);
            if (lq >= 1) Bv = fmaf(A0[mi], p, Bv);
            float p2 = __shfl_up(Bv, 32);
            if (lq >= 2) Bv = fmaf(A1[mi], p2, Bv);
            float e = __shfl_up(Bv, 16);
            exB[mi] = (lq == 0) ? 0.f : e;
            if (mi == 0) TB = __shfl(Bv, 48 + lr);
        }
        float hin0 = fmaf(exA[0], H0, exB[0]);
        float Hmid = fmaf(TA, H0, TB);
        float hin1 = fmaf(exA[1], Hmid, exB[1]);
        #pragma unroll
        for (int mi = 0; mi < 2; ++mi) {
            float hin = mi ? hin1 : hin0;
            #pragma unroll
            for (int r = 0; r < 4; ++r) {
                float h  = fmaf(pa[mi][r], hin, hloc[mi][r]);
                float yc = accC[mi][ni][r] * h;
                Ps[(hh*32 + mi*16 + lq*4 + r) * PST + ch] = f2bf(yc);
            }
        }
    }
    __syncthreads();

    // ---- vectorized gated epilogue: y = yc + D*xi; y *= silu(z); store uint4 ----
    #pragma unroll
    for (int p = 0; p < 4; ++p) {
        int e = p * 2048 + tid * 8, r = e >> 7, c = e & 127;
        uint4 yv = *(const uint4*)&Ps[r * PST + c];
        uint4 xv = *(const uint4*)&Xs[r * PST + c];
        float4 d0 = *(const float4*)(Dvf + c0 + c);
        float4 d1 = *(const float4*)(Dvf + c0 + c + 4);
        uint4 zv = *(const uint4*)(xz + (size_t)(srow + r) * (2*D_INNER) + D_INNER + c0 + c);
        float y0 = lo16(yv.x) + d0.x * lo16(xv.x);
        float y1 = hi16(yv.x) + d0.y * hi16(xv.x);
        float y2 = lo16(yv.y) + d0.z * lo16(xv.y);
        float y3 = hi16(yv.y) + d0.w * hi16(xv.y);
        float y4 = lo16(yv.z) + d1.x * lo16(xv.z);
        float y5 = hi16(yv.z) + d1.y * hi16(xv.z);
        float y6 = lo16(yv.w) + d1.z * lo16(xv.w);
        float y7 = hi16(yv.w) + d1.w * hi16(xv.w);
        float z0 = lo16(zv.x), z1 = hi16(zv.x), z2 = lo16(zv.y), z3 = hi16(zv.y);
        float z4 = lo16(zv.z), z5 = hi16(zv.z), z6 = lo16(zv.w), z7 = hi16(zv.w);
        y0 *= z0 / (1.f + expf(-z0)); y1 *= z1 / (1.f + expf(-z1));
        y2 *= z2 / (1.f + expf(-z2)); y3 *= z3 / (1.f + expf(-z3));
        y4 *= z4 / (1.f + expf(-z4)); y5 *= z5 / (1.f + expf(-z5));
        y6 *= z6 / (1.f + expf(-z6)); y7 *= z7 / (1.f + expf(-z7));
        uint4 o;
        o.x = pack2(y0, y1); o.y = pack2(y2, y3);
        o.z = pack2(y4, y5); o.w = pack2(y6, y7);
        *(uint4*)(ypre + (size_t)(srow + r) * D_INNER + c0 + c) = o;
    }
}

// ---------------- launcher ----------------
extern "C" void kernel_launch(void* const* d_in, const int* in_sizes, int n_in,
                              void* d_out, int out_size, void* d_ws, size_t ws_size,
                              hipStream_t stream) {
    const float* x     = (const float*)d_in[0];   // [8192][1024]
    const float* W_in  = (const float*)d_in[1];   // [1024][4096]
    const float* W_xp  = (const float*)d_in[2];   // [2048][129]
    const float* W_B   = (const float*)d_in[3];   // [64][2048]
    const float* W_C   = (const float*)d_in[4];   // [64][2048]
    const float* W_out = (const float*)d_in[5];   // [2048][1024]
    const float* Dv    = (const float*)d_in[6];   // [2048]
    const float* A_log = (const float*)d_in[7];   // [1]
    float* out = (float*)d_out;                   // [8192][1024] f32

    size_t off = 0;
    auto alloc = [&](size_t bytes) {
        void* p = (char*)d_ws + off; off += (bytes + 255) & ~(size_t)255; return p;
    };
    unsigned short* xbf   = (unsigned short*)alloc((size_t)MROWS * D_MODEL * 2);     // 16.8MB
    unsigned short* xz    = (unsigned short*)alloc((size_t)MROWS * 2 * D_INNER * 2); // 67MB
    unsigned short* ypre  = (unsigned short*)alloc((size_t)MROWS * D_INNER * 2);     // 33.5MB
    unsigned short* winT  = (unsigned short*)alloc((size_t)4096 * 1024 * 2);         // 8.4MB
    unsigned short* woutT = (unsigned short*)alloc((size_t)1024 * 2048 * 2);         // 4.2MB
    unsigned short* wbT   = (unsigned short*)alloc((size_t)2048 * 64 * 2);           // [2048][64]
    unsigned short* wcT   = (unsigned short*)alloc((size_t)2048 * 64 * 2);           // [2048][64]
    unsigned short* wxpT  = (unsigned short*)alloc((size_t)128 * 2048 * 2);          // [128][2048]
    unsigned short* projb = (unsigned short*)alloc((size_t)MROWS * 128 * 2);         // [8192][128]
    float* proj_part = (float*)alloc((size_t)4 * MROWS * 128 * 4);                   // 16.8MB
    float* w0f   = (float*)alloc(2048 * 4);
    float* dA    = (float*)alloc(MROWS * 4);
    float* abar  = (float*)alloc(MROWS * 4);
    float* sfx   = (float*)alloc(MROWS * 4);
    float* P     = (float*)alloc(BATCH * NCHUNK * 4);
    float* carry = (float*)alloc((size_t)BATCH * NCHUNK * D_INNER * 4);              // 2MB
    (void)ws_size; (void)n_in; (void)in_sizes; (void)out_size;

    // convert x to bf16
    hipLaunchKernelGGL(f32_to_bf16, dim3((MROWS * D_MODEL) / 1024), dim3(256), 0, stream, x, xbf);

    dim3 tb(32, 32);
    hipLaunchKernelGGL(transpose_f32_bf16, dim3(4096/32, 1024/32), tb, 0, stream, W_in,  winT, 1024, 4096);
    hipLaunchKernelGGL(transpose_f32_bf16, dim3(1024/32, 2048/32), tb, 0, stream, W_out, woutT, 2048, 1024);
    hipLaunchKernelGGL(transpose_f32_bf16, dim3(2048/32, 64/32),   tb, 0, stream, W_B,   wbT, 64, 2048);
    hipLaunchKernelGGL(transpose_f32_bf16, dim3(2048/32, 64/32),   tb, 0, stream, W_C,   wcT, 64, 2048);
    hipLaunchKernelGGL(transpose_wxp, dim3(4, 64), tb, 0, stream, W_xp, wxpT);
    hipLaunchKernelGGL(extract_w0, dim3(8), dim3(256), 0, stream, W_xp, w0f);

    // xz = x @ W_in   [8192][4096]
    hipLaunchKernelGGL((gemm_tn<EPI_PLAIN>), dim3(4096/BN, MROWS/BM), dim3(256), 0, stream,
                       xbf, winT, (void*)xz, MROWS, 4096, 1024, 1024, 1024, 4096);

    // delta / abar, then per-chunk suffix products
    hipLaunchKernelGGL(delta_kernel, dim3(MROWS/4), dim3(256), 0, stream, xz, w0f, A_log, dA, abar);
    hipLaunchKernelGGL(chunk_aux, dim3(1), dim3(BATCH*NCHUNK), 0, stream, dA, sfx, P);

    // proj = xi @ W_xp[:,1:129]  via split-K=4 (f32 partials) + reduce
    hipLaunchKernelGGL((gemm_tn<EPI_F32ACC>), dim3(1, MROWS/BM, 4), dim3(256), 0, stream,
                       xz, wxpT, (void*)proj_part, MROWS, 128, 512, 2*D_INNER, D_INNER, 128);
    hipLaunchKernelGGL(reduce_proj, dim3((MROWS * 128) / 1024), dim3(256), 0, stream,
                       proj_part, projb);

    // fused expansion + chunked scan
    hipLaunchKernelGGL(bc_carry, dim3(D_INNER/CB, SEQ/R2, BATCH), dim3(256), 0, stream,
                       projb, wbT, xz, sfx, carry);
    hipLaunchKernelGGL(scan_chunks, dim3(D_INNER/256, BATCH), dim3(256), 0, stream, carry, P);
    hipLaunchKernelGGL(bc_scan, dim3(D_INNER/CB, SEQ/R2, BATCH), dim3(256), 0, stream,
                       projb, wbT, wcT, xz, Dv, abar, carry, ypre);

    // out = ypre @ W_out   [8192][1024] f32
    hipLaunchKernelGGL((gemm_tn<EPI_F32OUT>), dim3(1024/BN, MROWS/BM), dim3(256), 0, stream,
                       ypre, woutT, (void*)out, MROWS, 1024, 2048, D_INNER, D_INNER, 1024);
}

// Round 7
// 341.014 us; speedup vs baseline: 1.0506x; 1.0506x over previous
//
#include <hip/hip_runtime.h>
#include <hip/hip_bf16.h>
#include <cstdint>
#include <cstddef>

// ---------------- problem constants ----------------
#define D_MODEL 1024
#define D_STATE 64
#define D_INNER 2048
#define BATCH   4
#define SEQ     2048
#define MROWS   (BATCH*SEQ)      // 8192
#define CHUNK   32               // scan chunk length
#define NCHUNK  (SEQ/CHUNK)      // 64 chunks per batch

typedef __bf16 bf16x8 __attribute__((ext_vector_type(8)));
typedef float  f32x4  __attribute__((ext_vector_type(4)));

__device__ __forceinline__ float bf2f(unsigned short u) {
    union { unsigned int i; float f; } v; v.i = ((unsigned int)u) << 16; return v.f;
}
__device__ __forceinline__ unsigned short f2bf(float f) {
    union { float f; unsigned int i; } v; v.f = f;
    unsigned int r = v.i + 0x7fff + ((v.i >> 16) & 1);   // round-to-nearest-even
    return (unsigned short)(r >> 16);
}
__device__ __forceinline__ float lo16(unsigned u){ return bf2f((unsigned short)(u & 0xffffu)); }
__device__ __forceinline__ float hi16(unsigned u){ return bf2f((unsigned short)(u >> 16)); }
__device__ __forceinline__ unsigned pack2(float a, float b){
    return (unsigned)f2bf(a) | ((unsigned)f2bf(b) << 16);
}

// ---------------- mega prep: x convert + all weight transposes + w0 extract ----------------
// 1D grid, 256 threads. Segments:
//  [0,4096)        x f32->bf16 (8 elems/thread)
//  [4096,8192)     W_in  [1024][4096] -> winT  [4096][1024]
//  [8192,10240)    W_out [2048][1024] -> woutT [1024][2048]
//  [10240,10368)   W_B   [64][2048]   -> wbT   [2048][64]
//  [10368,10496)   W_C   [64][2048]   -> wcT   [2048][64]
//  [10496,10752)   W_xp cols 1..128   -> wxpT  [128][2048]
//  [10752,10760)   W_xp col 0         -> w0f   [2048] f32
#define PREP_BLOCKS 10760
__global__ __launch_bounds__(256) void mega_prep(
    const float* __restrict__ x, const float* __restrict__ W_in,
    const float* __restrict__ W_xp, const float* __restrict__ W_B,
    const float* __restrict__ W_C, const float* __restrict__ W_out,
    unsigned short* __restrict__ xbf, unsigned short* __restrict__ winT,
    unsigned short* __restrict__ woutT, unsigned short* __restrict__ wbT,
    unsigned short* __restrict__ wcT, unsigned short* __restrict__ wxpT,
    float* __restrict__ w0f)
{
    __shared__ float t[32][33];
    int bid = blockIdx.x;
    const int tid = threadIdx.x;
    const int tx = tid & 31, ty8 = tid >> 5;   // 32 cols x 8 rows per pass

    if (bid < 4096) {                          // x convert
        size_t i = ((size_t)bid * 256 + tid) * 8;
        float4 v0 = *(const float4*)(x + i);
        float4 v1 = *(const float4*)(x + i + 4);
        uint4 o; o.x = pack2(v0.x, v0.y); o.y = pack2(v0.z, v0.w);
        o.z = pack2(v1.x, v1.y); o.w = pack2(v1.z, v1.w);
        *(uint4*)(xbf + i) = o;
        return;
    }
    bid -= 4096;
    if (bid < 4096) {                          // W_in transpose
        int bx = (bid & 127) * 32, by = (bid >> 7) * 32;
        #pragma unroll
        for (int k = 0; k < 4; ++k) { int r = ty8 + k*8; t[r][tx] = W_in[(size_t)(by+r)*4096 + bx+tx]; }
        __syncthreads();
        #pragma unroll
        for (int k = 0; k < 4; ++k) { int r = ty8 + k*8; winT[(size_t)(bx+r)*1024 + by+tx] = f2bf(t[tx][r]); }
        return;
    }
    bid -= 4096;
    if (bid < 2048) {                          // W_out transpose
        int bx = (bid & 31) * 32, by = (bid >> 5) * 32;
        #pragma unroll
        for (int k = 0; k < 4; ++k) { int r = ty8 + k*8; t[r][tx] = W_out[(size_t)(by+r)*1024 + bx+tx]; }
        __syncthreads();
        #pragma unroll
        for (int k = 0; k < 4; ++k) { int r = ty8 + k*8; woutT[(size_t)(bx+r)*2048 + by+tx] = f2bf(t[tx][r]); }
        return;
    }
    bid -= 2048;
    if (bid < 128) {                           // W_B transpose
        int bx = (bid & 63) * 32, by = (bid >> 6) * 32;
        #pragma unroll
        for (int k = 0; k < 4; ++k) { int r = ty8 + k*8; t[r][tx] = W_B[(size_t)(by+r)*2048 + bx+tx]; }
        __syncthreads();
        #pragma unroll
        for (int k = 0; k < 4; ++k) { int r = ty8 + k*8; wbT[(size_t)(bx+r)*64 + by+tx] = f2bf(t[tx][r]); }
        return;
    }
    bid -= 128;
    if (bid < 128) {                           // W_C transpose
        int bx = (bid & 63) * 32, by = (bid >> 6) * 32;
        #pragma unroll
        for (int k = 0; k < 4; ++k) { int r = ty8 + k*8; t[r][tx] = W_C[(size_t)(by+r)*2048 + bx+tx]; }
        __syncthreads();
        #pragma unroll
        for (int k = 0; k < 4; ++k) { int r = ty8 + k*8; wcT[(size_t)(bx+r)*64 + by+tx] = f2bf(t[tx][r]); }
        return;
    }
    bid -= 128;
    if (bid < 256) {                           // W_xp cols 1..128 transpose
        int j0 = (bid & 3) * 32, k0 = (bid >> 2) * 32;
        #pragma unroll
        for (int k = 0; k < 4; ++k) { int r = ty8 + k*8; t[r][tx] = W_xp[(size_t)(k0+r)*129 + 1 + j0+tx]; }
        __syncthreads();
        #pragma unroll
        for (int k = 0; k < 4; ++k) { int r = ty8 + k*8; wxpT[(size_t)(j0+r)*2048 + k0+tx] = f2bf(t[tx][r]); }
        return;
    }
    bid -= 256;
    {                                          // w0 extract
        int k = bid * 256 + tid;
        w0f[k] = W_xp[(size_t)k * 129];
    }
}

// ---------------- MFMA GEMM (TN): C[M][N] = A[M][K] @ BT[N][K]^T ----------------
#define BM 128
#define BN 128
enum { EPI_PLAIN = 0, EPI_F32OUT = 3, EPI_F32ACC = 4 };

__device__ __forceinline__ void gload_lds16(const void* g, void* l) {
    __builtin_amdgcn_global_load_lds((const __attribute__((address_space(1))) void*)g,
                                     (__attribute__((address_space(3))) void*)l, 16, 0, 0);
}

template<int EPI>
__global__ __launch_bounds__(256) void gemm_tn(
    const unsigned short* __restrict__ A,   // [M][K] lda (bf16)
    const unsigned short* __restrict__ BT,  // [N][K] ldb (bf16)
    void* __restrict__ Cv,                  // [M][N] ldc
    int M, int N, int kchunk, int lda, int ldb, int ldc)
{
    __shared__ __align__(16) unsigned short As0[BM * 32];
    __shared__ __align__(16) unsigned short As1[BM * 32];
    __shared__ __align__(16) unsigned short Bs0[BN * 32];
    __shared__ __align__(16) unsigned short Bs1[BN * 32];
    const int tid  = threadIdx.x;
    const int wave = tid >> 6, lane = tid & 63;
    const int row0 = blockIdx.y * BM, col0 = blockIdx.x * BN;
    const int wr = (wave >> 1) * 64, wc = (wave & 1) * 64;
    const int srow = lane >> 2;          // 0..15
    const int scol = (lane & 3) * 8;     // 0,8,16,24

    f32x4 acc[4][4];
    #pragma unroll
    for (int i = 0; i < 4; ++i)
        #pragma unroll
        for (int j = 0; j < 4; ++j)
            #pragma unroll
            for (int r = 0; r < 4; ++r) acc[i][j][r] = 0.0f;

    const int kbeg = blockIdx.z * kchunk;
    for (int k0 = kbeg; k0 < kbeg + kchunk; k0 += 64) {
        #pragma unroll
        for (int qi = 0; qi < 2; ++qi) {
            int q = wave * 2 + qi;   // 0..7: 16-row group of the 128-row tile
            const unsigned short* gA = A  + (size_t)(row0 + q*16 + srow) * lda + (k0 + scol);
            const unsigned short* gB = BT + (size_t)(col0 + q*16 + srow) * ldb + (k0 + scol);
            gload_lds16(gA,      &As0[q * 512]);
            gload_lds16(gA + 32, &As1[q * 512]);
            gload_lds16(gB,      &Bs0[q * 512]);
            gload_lds16(gB + 32, &Bs1[q * 512]);
        }
        __syncthreads();
        bf16x8 af0[4], af1[4], bf0[4], bf1[4];
        const int lro = lane & 15, lko = (lane >> 4) * 8;
        #pragma unroll
        for (int t = 0; t < 4; ++t) {
            af0[t] = *(const bf16x8*)&As0[(wr + t*16 + lro) * 32 + lko];
            af1[t] = *(const bf16x8*)&As1[(wr + t*16 + lro) * 32 + lko];
            bf0[t] = *(const bf16x8*)&Bs0[(wc + t*16 + lro) * 32 + lko];
            bf1[t] = *(const bf16x8*)&Bs1[(wc + t*16 + lro) * 32 + lko];
        }
        #pragma unroll
        for (int i = 0; i < 4; ++i)
            #pragma unroll
            for (int j = 0; j < 4; ++j) {
                acc[i][j] = __builtin_amdgcn_mfma_f32_16x16x32_bf16(af0[i], bf0[j], acc[i][j], 0, 0, 0);
                acc[i][j] = __builtin_amdgcn_mfma_f32_16x16x32_bf16(af1[i], bf1[j], acc[i][j], 0, 0, 0);
            }
        __syncthreads();
    }

    const int r0 = (lane >> 4) * 4, cl = lane & 15;
    #pragma unroll
    for (int i = 0; i < 4; ++i) {
        #pragma unroll
        for (int j = 0; j < 4; ++j) {
            #pragma unroll
            for (int r = 0; r < 4; ++r) {
                int gr = row0 + wr + i*16 + r0 + r;
                int gc = col0 + wc + j*16 + cl;
                float v = acc[i][j][r];
                if (EPI == EPI_F32OUT)      ((float*)Cv)[(size_t)gr * ldc + gc] = v;
                else if (EPI == EPI_F32ACC) ((float*)Cv + (size_t)blockIdx.z * M * ldc)[(size_t)gr * ldc + gc] = v;
                else                        ((unsigned short*)Cv)[(size_t)gr * ldc + gc] = f2bf(v);
            }
        }
    }
}

// ---------------- reduce split-K partials -> bf16 ----------------
__global__ __launch_bounds__(256) void reduce_proj(const float* __restrict__ part,
                                                   unsigned short* __restrict__ out) {
    size_t i = ((size_t)blockIdx.x * 256 + threadIdx.x) * 4;
    const size_t stride = (size_t)MROWS * 128;
    float4 s = *(const float4*)(part + i);
    #pragma unroll
    for (int p = 1; p < 4; ++p) {
        float4 v = *(const float4*)(part + p * stride + i);
        s.x += v.x; s.y += v.y; s.z += v.z; s.w += v.w;
    }
    uint2 o; o.x = pack2(s.x, s.y); o.y = pack2(s.z, s.w);
    *(uint2*)(out + i) = o;
}

// ---------------- fused delta + chunk aux: one block per chunk (32 rows) ----------------
// Per row m: dA = softplus(xi[m,:].w0) * A ; abar[m] = exp(dA).
// Per chunk: sfx[t] = exp(sum_{s>t} dA), P = exp(sum dA).
__global__ __launch_bounds__(256) void delta_chunk(
    const unsigned short* __restrict__ xz, const float* __restrict__ w0f,
    const float* __restrict__ A_log,
    float* __restrict__ abar, float* __restrict__ sfx, float* __restrict__ P)
{
    __shared__ float dAs[CHUNK];
    const int chunk = blockIdx.x;            // 0..255 = b*NCHUNK + j
    const int wave = threadIdx.x >> 6, lane = threadIdx.x & 63;
    const float Av = -expf(A_log[0]);
    #pragma unroll
    for (int rr = 0; rr < 8; ++rr) {
        int row = chunk * CHUNK + wave * 8 + rr;
        const unsigned short* xi = xz + (size_t)row * (2 * D_INNER);
        float s = 0.f;
        #pragma unroll
        for (int step = 0; step < 4; ++step) {
            int oct = step * 64 + lane;
            uint4 u = *(const uint4*)(xi + oct * 8);
            const float4* pw = (const float4*)(w0f + oct * 8);
            float4 wa = pw[0], wb = pw[1];
            s += lo16(u.x)*wa.x + hi16(u.x)*wa.y + lo16(u.y)*wa.z + hi16(u.y)*wa.w
               + lo16(u.z)*wb.x + hi16(u.z)*wb.y + lo16(u.w)*wb.z + hi16(u.w)*wb.w;
        }
        #pragma unroll
        for (int off = 32; off > 0; off >>= 1) s += __shfl_xor(s, off);
        if (lane == 0) {
            float d  = (s > 20.f) ? s : log1pf(expf(s));
            float da = d * Av;
            dAs[wave * 8 + rr] = da;
            abar[row] = expf(da);
        }
    }
    __syncthreads();
    if (threadIdx.x == 0) {
        float suf = 0.f;
        for (int t = CHUNK - 1; t >= 0; --t) {
            sfx[chunk * CHUNK + t] = expf(suf);
            suf += dAs[t];
        }
        P[chunk] = expf(suf);
    }
}

// ============ fused B/C expansion + scan kernels ============
#define CB 128
#define R2 64
#define PST 136   // padded LDS row stride (elems)

// ---------------- pass 1: carry[j][c] = sum_t sfx[t] * B[t][c] * xi[t][c] ----------------
__global__ __launch_bounds__(256) void bc_carry(
    const unsigned short* __restrict__ proj,  // [MROWS][128] bf16 (B_raw|C_raw)
    const unsigned short* __restrict__ wbT,   // [2048][64] bf16
    const unsigned short* __restrict__ xz,    // [MROWS][4096] bf16 (xi = cols 0..2047)
    const float* __restrict__ sfx,            // [MROWS]
    float* __restrict__ carry)                // [BATCH*NCHUNK][2048]
{
    __shared__ unsigned short Ps[R2 * PST];   // proj tile (cols 0..127 valid)
    __shared__ unsigned short Xs[R2 * PST];   // xi tile (channel slice)
    const int cb = blockIdx.x, j2 = blockIdx.y, b = blockIdx.z;
    const int c0 = cb * CB;
    const int srow = b * SEQ + j2 * R2;
    const int tid = threadIdx.x, wave = tid >> 6, lane = tid & 63;

    #pragma unroll
    for (int i = 0; i < 4; ++i) {             // stage proj tile 64x128
        int e = i * 2048 + tid * 8, r = e >> 7, c = e & 127;
        uint4 v = *(const uint4*)(proj + (size_t)(srow + r) * 128 + c);
        *(uint4*)&Ps[r * PST + c] = v;
    }
    #pragma unroll
    for (int i = 0; i < 4; ++i) {             // stage xi tile 64x128
        int e = i * 2048 + tid * 8, r = e >> 7, c = e & 127;
        uint4 v = *(const uint4*)(xz + (size_t)(srow + r) * (2*D_INNER) + c0 + c);
        *(uint4*)&Xs[r * PST + c] = v;
    }
    __syncthreads();

    const int mt0 = (wave >> 1) * 2;          // waves 0,1 -> chunk A rows; 2,3 -> chunk B
    const int nb  = (wave & 1) * 64;
    const int lr = lane & 15, lq = lane >> 4;

    f32x4 acc[2][4];
    #pragma unroll
    for (int mi = 0; mi < 2; ++mi)
        #pragma unroll
        for (int ni = 0; ni < 4; ++ni)
            #pragma unroll
            for (int r = 0; r < 4; ++r) acc[mi][ni][r] = 0.0f;

    #pragma unroll
    for (int s = 0; s < 2; ++s) {             // K=64: two k-steps
        bf16x8 af[2], bfr[4];
        #pragma unroll
        for (int mi = 0; mi < 2; ++mi)
            af[mi] = *(const bf16x8*)&Ps[((mt0+mi)*16 + lr) * PST + s*32 + lq*8];
        #pragma unroll
        for (int ni = 0; ni < 4; ++ni)
            bfr[ni] = *(const bf16x8*)(wbT + (size_t)(c0 + nb + ni*16 + lr) * 64 + s*32 + lq*8);
        #pragma unroll
        for (int mi = 0; mi < 2; ++mi)
            #pragma unroll
            for (int ni = 0; ni < 4; ++ni)
                acc[mi][ni] = __builtin_amdgcn_mfma_f32_16x16x32_bf16(af[mi], bfr[ni], acc[mi][ni], 0, 0, 0);
    }

    float w8[2][4];
    #pragma unroll
    for (int mi = 0; mi < 2; ++mi)
        #pragma unroll
        for (int r = 0; r < 4; ++r)
            w8[mi][r] = sfx[srow + (mt0+mi)*16 + lq*4 + r];

    float csum[4];
    #pragma unroll
    for (int ni = 0; ni < 4; ++ni) {
        float s = 0.f;
        #pragma unroll
        for (int mi = 0; mi < 2; ++mi)
            #pragma unroll
            for (int r = 0; r < 4; ++r) {
                int row = (mt0+mi)*16 + lq*4 + r;
                float xv = bf2f(Xs[row * PST + nb + ni*16 + lr]);
                s += w8[mi][r] * acc[mi][ni][r] * xv;
            }
        s += __shfl_xor(s, 16);
        s += __shfl_xor(s, 32);
        csum[ni] = s;
    }
    if (lane < 16) {
        int jj = j2 * 2 + (mt0 >> 1);
        float* dst = carry + ((size_t)(b * NCHUNK + jj)) * D_INNER + c0 + nb;
        #pragma unroll
        for (int ni = 0; ni < 4; ++ni) dst[ni*16 + lane] = csum[ni];
    }
}

// ---------------- pass 2: inter-chunk scan; carry <- exclusive prefix (h-init) ------
__global__ __launch_bounds__(256) void scan_chunks(float* __restrict__ carry,
                                                   const float* __restrict__ P) {
    int c = blockIdx.x * 256 + threadIdx.x;
    int b = blockIdx.y;
    float H = 0.f;
    for (int j = 0; j < NCHUNK; ++j) {
        size_t idx = ((size_t)(b * NCHUNK + j)) * D_INNER + c;
        float cr = carry[idx];
        carry[idx] = H;                         // exclusive: h-init for chunk j
        H = P[b * NCHUNK + j] * H + cr;
    }
}

// ---------------- pass 3: MFMA-recompute B,C (f32 regs); register scan with shuffle
//                  carries; vectorized gated epilogue -> ypre ----------------
__global__ __launch_bounds__(256) void bc_scan(
    const unsigned short* __restrict__ proj,
    const unsigned short* __restrict__ wbT,   // [2048][64]
    const unsigned short* __restrict__ wcT,   // [2048][64]
    const unsigned short* __restrict__ xz,
    const float* __restrict__ Dvf,
    const float* __restrict__ abar,
    const float* __restrict__ carry,
    unsigned short* __restrict__ ypre)        // [MROWS][2048]
{
    __shared__ unsigned short Ps[R2 * PST];   // proj tile, later reused as Y tile
    __shared__ unsigned short Xs[R2 * PST];   // xi tile
    __shared__ float Aab[R2];                 // abar for the block's 64 rows
    const int cb = blockIdx.x, j2 = blockIdx.y, b = blockIdx.z;
    const int c0 = cb * CB;
    const int srow = b * SEQ + j2 * R2;
    const int tid = threadIdx.x, wave = tid >> 6, lane = tid & 63;

    #pragma unroll
    for (int i = 0; i < 4; ++i) {
        int e = i * 2048 + tid * 8, r = e >> 7, c = e & 127;
        uint4 v = *(const uint4*)(proj + (size_t)(srow + r) * 128 + c);
        *(uint4*)&Ps[r * PST + c] = v;
    }
    #pragma unroll
    for (int i = 0; i < 4; ++i) {
        int e = i * 2048 + tid * 8, r = e >> 7, c = e & 127;
        uint4 v = *(const uint4*)(xz + (size_t)(srow + r) * (2*D_INNER) + c0 + c);
        *(uint4*)&Xs[r * PST + c] = v;
    }
    if (tid < R2) Aab[tid] = abar[srow + tid];
    __syncthreads();

    const int hh = wave >> 1;                 // chunk half within block (0/1)
    const int nb = (wave & 1) * 64;
    const int lr = lane & 15, lq = lane >> 4;
    const int jj = j2 * 2 + hh;

    // ---- MFMA: B-tile and C-tile into f32 registers (C-layout) ----
    f32x4 accB[2][4], accC[2][4];
    #pragma unroll
    for (int mi = 0; mi < 2; ++mi)
        #pragma unroll
        for (int ni = 0; ni < 4; ++ni)
            #pragma unroll
            for (int r = 0; r < 4; ++r) { accB[mi][ni][r] = 0.f; accC[mi][ni][r] = 0.f; }
    #pragma unroll
    for (int s = 0; s < 2; ++s) {
        bf16x8 afB[2], afC[2], bB[4], bC[4];
        #pragma unroll
        for (int mi = 0; mi < 2; ++mi) {
            afB[mi] = *(const bf16x8*)&Ps[(hh*32 + mi*16 + lr) * PST + s*32 + lq*8];
            afC[mi] = *(const bf16x8*)&Ps[(hh*32 + mi*16 + lr) * PST + 64 + s*32 + lq*8];
        }
        #pragma unroll
        for (int ni = 0; ni < 4; ++ni) {
            bB[ni] = *(const bf16x8*)(wbT + (size_t)(c0 + nb + ni*16 + lr) * 64 + s*32 + lq*8);
            bC[ni] = *(const bf16x8*)(wcT + (size_t)(c0 + nb + ni*16 + lr) * 64 + s*32 + lq*8);
        }
        #pragma unroll
        for (int mi = 0; mi < 2; ++mi)
            #pragma unroll
            for (int ni = 0; ni < 4; ++ni) {
                accB[mi][ni] = __builtin_amdgcn_mfma_f32_16x16x32_bf16(afB[mi], bB[ni], accB[mi][ni], 0, 0, 0);
                accC[mi][ni] = __builtin_amdgcn_mfma_f32_16x16x32_bf16(afC[mi], bC[ni], accC[mi][ni], 0, 0, 0);
            }
    }
    __syncthreads();   // all waves done reading Ps -> safe to reuse as Y

    // ---- decay values & prefix products (channel-independent) ----
    float ar[2][4], pa[2][4];
    #pragma unroll
    for (int mi = 0; mi < 2; ++mi) {
        float p = 1.f;
        #pragma unroll
        for (int r = 0; r < 4; ++r) {
            ar[mi][r] = Aab[hh*32 + mi*16 + lq*4 + r];
            p *= ar[mi][r];
            pa[mi][r] = p;
        }
    }
    float A0[2], A1[2], A2[2], exA[2];
    #pragma unroll
    for (int mi = 0; mi < 2; ++mi) {
        A0[mi] = pa[mi][3];
        float p = __shfl_up(A0[mi], 16);
        A1[mi] = (lq >= 1) ? p * A0[mi] : A0[mi];
        float p2 = __shfl_up(A1[mi], 32);
        A2[mi] = (lq >= 2) ? p2 * A1[mi] : A1[mi];
        float e = __shfl_up(A2[mi], 16);
        exA[mi] = (lq == 0) ? 1.f : e;
    }
    const float TA = __shfl(A2[0], 48 + lr);   // inclusive product over chunk-half 0

    // ---- per-channel scan + y ----
    #pragma unroll
    for (int ni = 0; ni < 4; ++ni) {
        const int ch = nb + ni*16 + lr;
        float H0 = carry[((size_t)(b * NCHUNK + jj)) * D_INNER + c0 + ch];
        float hloc[2][4];
        #pragma unroll
        for (int mi = 0; mi < 2; ++mi) {
            float h = 0.f;
            #pragma unroll
            for (int r = 0; r < 4; ++r) {
                float xv = bf2f(Xs[(hh*32 + mi*16 + lq*4 + r) * PST + ch]);
                h = fmaf(ar[mi][r], h, accB[mi][ni][r] * xv);
                hloc[mi][r] = h;
            }
        }
        float exB[2], TB = 0.f;
        #pragma unroll
        for (int mi = 0; mi < 2; ++mi) {
            float Bv = hloc[mi][3];
            float p = __shfl_up(Bv, 16);
            if (lq >= 1) Bv = fmaf(A0[mi], p, Bv);
            float p2 = __shfl_up(Bv, 32);
            if (lq >= 2) Bv = fmaf(A1[mi], p2, Bv);
            float e = __shfl_up(Bv, 16);
            exB[mi] = (lq == 0) ? 0.f : e;
            if (mi == 0) TB = __shfl(Bv, 48 + lr);
        }
        float hin0 = fmaf(exA[0], H0, exB[0]);
        float Hmid = fmaf(TA, H0, TB);
        float hin1 = fmaf(exA[1], Hmid, exB[1]);
        #pragma unroll
        for (int mi = 0; mi < 2; ++mi) {
            float hin = mi ? hin1 : hin0;
            #pragma unroll
            for (int r = 0; r < 4; ++r) {
                float h  = fmaf(pa[mi][r], hin, hloc[mi][r]);
                float yc = accC[mi][ni][r] * h;
                Ps[(hh*32 + mi*16 + lq*4 + r) * PST + ch] = f2bf(yc);
            }
        }
    }
    __syncthreads();

    // ---- vectorized gated epilogue: y = yc + D*xi; y *= silu(z); store uint4 ----
    #pragma unroll
    for (int p = 0; p < 4; ++p) {
        int e = p * 2048 + tid * 8, r = e >> 7, c = e & 127;
        uint4 yv = *(const uint4*)&Ps[r * PST + c];
        uint4 xv = *(const uint4*)&Xs[r * PST + c];
        float4 d0 = *(const float4*)(Dvf + c0 + c);
        float4 d1 = *(const float4*)(Dvf + c0 + c + 4);
        uint4 zv = *(const uint4*)(xz + (size_t)(srow + r) * (2*D_INNER) + D_INNER + c0 + c);
        float y0 = lo16(yv.x) + d0.x * lo16(xv.x);
        float y1 = hi16(yv.x) + d0.y * hi16(xv.x);
        float y2 = lo16(yv.y) + d0.z * lo16(xv.y);
        float y3 = hi16(yv.y) + d0.w * hi16(xv.y);
        float y4 = lo16(yv.z) + d1.x * lo16(xv.z);
        float y5 = hi16(yv.z) + d1.y * hi16(xv.z);
        float y6 = lo16(yv.w) + d1.z * lo16(xv.w);
        float y7 = hi16(yv.w) + d1.w * hi16(xv.w);
        float z0 = lo16(zv.x), z1 = hi16(zv.x), z2 = lo16(zv.y), z3 = hi16(zv.y);
        float z4 = lo16(zv.z), z5 = hi16(zv.z), z6 = lo16(zv.w), z7 = hi16(zv.w);
        y0 *= z0 / (1.f + expf(-z0)); y1 *= z1 / (1.f + expf(-z1));
        y2 *= z2 / (1.f + expf(-z2)); y3 *= z3 / (1.f + expf(-z3));
        y4 *= z4 / (1.f + expf(-z4)); y5 *= z5 / (1.f + expf(-z5));
        y6 *= z6 / (1.f + expf(-z6)); y7 *= z7 / (1.f + expf(-z7));
        uint4 o;
        o.x = pack2(y0, y1); o.y = pack2(y2, y3);
        o.z = pack2(y4, y5); o.w = pack2(y6, y7);
        *(uint4*)(ypre + (size_t)(srow + r) * D_INNER + c0 + c) = o;
    }
}

// ---------------- launcher ----------------
extern "C" void kernel_launch(void* const* d_in, const int* in_sizes, int n_in,
                              void* d_out, int out_size, void* d_ws, size_t ws_size,
                              hipStream_t stream) {
    const float* x     = (const float*)d_in[0];   // [8192][1024]
    const float* W_in  = (const float*)d_in[1];   // [1024][4096]
    const float* W_xp  = (const float*)d_in[2];   // [2048][129]
    const float* W_B   = (const float*)d_in[3];   // [64][2048]
    const float* W_C   = (const float*)d_in[4];   // [64][2048]
    const float* W_out = (const float*)d_in[5];   // [2048][1024]
    const float* Dv    = (const float*)d_in[6];   // [2048]
    const float* A_log = (const float*)d_in[7];   // [1]
    float* out = (float*)d_out;                   // [8192][1024] f32

    size_t off = 0;
    auto alloc = [&](size_t bytes) {
        void* p = (char*)d_ws + off; off += (bytes + 255) & ~(size_t)255; return p;
    };
    unsigned short* xbf   = (unsigned short*)alloc((size_t)MROWS * D_MODEL * 2);     // 16.8MB
    unsigned short* xz    = (unsigned short*)alloc((size_t)MROWS * 2 * D_INNER * 2); // 67MB
    unsigned short* ypre  = (unsigned short*)alloc((size_t)MROWS * D_INNER * 2);     // 33.5MB
    unsigned short* winT  = (unsigned short*)alloc((size_t)4096 * 1024 * 2);         // 8.4MB
    unsigned short* woutT = (unsigned short*)alloc((size_t)1024 * 2048 * 2);         // 4.2MB
    unsigned short* wbT   = (unsigned short*)alloc((size_t)2048 * 64 * 2);           // [2048][64]
    unsigned short* wcT   = (unsigned short*)alloc((size_t)2048 * 64 * 2);           // [2048][64]
    unsigned short* wxpT  = (unsigned short*)alloc((size_t)128 * 2048 * 2);          // [128][2048]
    unsigned short* projb = (unsigned short*)alloc((size_t)MROWS * 128 * 2);         // [8192][128]
    float* proj_part = (float*)alloc((size_t)4 * MROWS * 128 * 4);                   // 16.8MB
    float* w0f   = (float*)alloc(2048 * 4);
    float* abar  = (float*)alloc(MROWS * 4);
    float* sfx   = (float*)alloc(MROWS * 4);
    float* P     = (float*)alloc(BATCH * NCHUNK * 4);
    float* carry = (float*)alloc((size_t)BATCH * NCHUNK * D_INNER * 4);              // 2MB
    (void)ws_size; (void)n_in; (void)in_sizes; (void)out_size;

    // all input prep in one dispatch
    hipLaunchKernelGGL(mega_prep, dim3(PREP_BLOCKS), dim3(256), 0, stream,
                       x, W_in, W_xp, W_B, W_C, W_out,
                       xbf, winT, woutT, wbT, wcT, wxpT, w0f);

    // xz = x @ W_in   [8192][4096]
    hipLaunchKernelGGL((gemm_tn<EPI_PLAIN>), dim3(4096/BN, MROWS/BM), dim3(256), 0, stream,
                       xbf, winT, (void*)xz, MROWS, 4096, 1024, 1024, 1024, 4096);

    // delta/abar + per-chunk suffix products (fused)
    hipLaunchKernelGGL(delta_chunk, dim3(BATCH*NCHUNK), dim3(256), 0, stream,
                       xz, w0f, A_log, abar, sfx, P);

    // proj = xi @ W_xp[:,1:129]  via split-K=4 (f32 partials) + reduce
    hipLaunchKernelGGL((gemm_tn<EPI_F32ACC>), dim3(1, MROWS/BM, 4), dim3(256), 0, stream,
                       xz, wxpT, (void*)proj_part, MROWS, 128, 512, 2*D_INNER, D_INNER, 128);
    hipLaunchKernelGGL(reduce_proj, dim3((MROWS * 128) / 1024), dim3(256), 0, stream,
                       proj_part, projb);

    // fused expansion + chunked scan
    hipLaunchKernelGGL(bc_carry, dim3(D_INNER/CB, SEQ/R2, BATCH), dim3(256), 0, stream,
                       projb, wbT, xz, sfx, carry);
    hipLaunchKernelGGL(scan_chunks, dim3(D_INNER/256, BATCH), dim3(256), 0, stream, carry, P);
    hipLaunchKernelGGL(bc_scan, dim3(D_INNER/CB, SEQ/R2, BATCH), dim3(256), 0, stream,
                       projb, wbT, wcT, xz, Dv, abar, carry, ypre);

    // out = ypre @ W_out   [8192][1024] f32
    hipLaunchKernelGGL((gemm_tn<EPI_F32OUT>), dim3(1024/BN, MROWS/BM), dim3(256), 0, stream,
                       ypre, woutT, (void*)out, MROWS, 1024, 2048, D_INNER, D_INNER, 1024);
}